// Round 8
// baseline (112.177 us; speedup 1.0000x reference)
//
#include <hip/hip_runtime.h>
#include <hip/hip_bf16.h>
#include <math.h>

// Problem dims
#define TOK   8192
#define KDIM  8192
#define F_DIM 64
#define U_DIM 128
#define N3    384

// GEMM tiling
#define BM    64
#define BK    64
#define KSPL  4
#define KRANGE (KDIM / KSPL)     // 2048
#define NST   (KRANGE / BK)      // 32
#define NHALF (NST * 2)          // 64 half-steps
#define NF    (KRANGE / U_DIM)   // 16
#define ASTR  72
#define BSTEP_ELEM  (N3 * BK)    // 24576 bf16 (48 KB)
#define BHALF_ELEM  (N3 * 32)    // 12288 bf16 (24 KB)
#define BSTEP_BYTES (BSTEP_ELEM * 2)
#define BHALF_BYTES (BHALF_ELEM * 2)

typedef __bf16 bf16x8 __attribute__((ext_vector_type(8)));
typedef float  f32x4  __attribute__((ext_vector_type(4)));

// lgkmcnt-only barrier: LDS ops drained; VMEM/gload_lds stay in flight
#define WG_SYNC() do {                                       \
    asm volatile("s_waitcnt lgkmcnt(0)" ::: "memory");       \
    __builtin_amdgcn_s_barrier();                            \
    __builtin_amdgcn_sched_barrier(0);                       \
} while (0)

// tanh-approx GELU: z - z/(1 + 2^(z*(2.30234 + 0.102955 z^2))), |err| < ~1e-3
__device__ __forceinline__ float gelu_fast(float z) {
    float t = z * z;
    float s = fmaf(0.1029551f, t, 2.3023457f);
    float e = __builtin_amdgcn_exp2f(z * s);
    float r = __builtin_amdgcn_rcpf(e + 1.0f);   // +inf -> 0
    return fmaf(-z, r, z);
}

__device__ __forceinline__ float bflo(unsigned u) { u <<= 16; return __builtin_bit_cast(float, u); }
__device__ __forceinline__ float bfhi(unsigned u) { u &= 0xffff0000u; return __builtin_bit_cast(float, u); }

// async global->LDS, 16B/lane: dest wave-uniform base, src per-lane
__device__ __forceinline__ void gload16(const void* g, void* l, int lane) {
    __builtin_amdgcn_global_load_lds(
        (const __attribute__((address_space(1))) unsigned int*)((const char*)g + lane * 16),
        (__attribute__((address_space(3))) unsigned int*)l, 16, 0, 0);
}

// ---------------------------------------------------------------------------
// Kernel 1: pack W[k][n] f32 (3 mats) into the GEMM's LDS image:
// Bp[(s*32+st)*24576 + ((ksi*4 + p)*384 + n)*8 + j], where
// k = s*2048 + st*64 + ksi*32 + p*8 + j, n = mat*128 + u.
// Each 24KB half-step is one contiguous, conflict-free LDS image.
// Block 768 packs lin_w -> bf16-pair linp[128][64].
// ---------------------------------------------------------------------------
__global__ __launch_bounds__(256) void vsn_prep8(
    const float* __restrict__ elu_w,
    const float* __restrict__ gate_w,
    const float* __restrict__ proj_w,
    const float* __restrict__ lin_w,
    __bf16* __restrict__ Bp,
    unsigned* __restrict__ linp)
{
    const int t = threadIdx.x;
    if (blockIdx.x == 3 * (KDIM / 32)) {
#pragma unroll
        for (int i = 0; i < 32; ++i) {
            int idx = i * 256 + t;            // 0..8191
            int v = idx >> 6, l = idx & 63;
            __bf16 ba = (__bf16)lin_w[v * U_DIM + 2 * l];
            __bf16 bb = (__bf16)lin_w[v * U_DIM + 2 * l + 1];
            unsigned pa = (unsigned)__builtin_bit_cast(unsigned short, ba);
            unsigned pb = (unsigned)__builtin_bit_cast(unsigned short, bb);
            linp[idx] = pa | (pb << 16);
        }
        return;
    }
    __shared__ float tile[32][U_DIM + 1];
    const int mat = blockIdx.x / (KDIM / 32);   // 0..2
    const int kb  = blockIdx.x % (KDIM / 32);   // 32 k-rows each
    const float* W = (mat == 0) ? elu_w : (mat == 1 ? gate_w : proj_w);

#pragma unroll
    for (int i = 0; i < 16; ++i) {
        int idx = i * 256 + t;
        int r = idx >> 7, c = idx & 127;
        tile[r][c] = W[(size_t)(kb * 32 + r) * U_DIM + c];
    }
    __syncthreads();

    const int s   = kb >> 6;           // k-split
    const int st  = (kb & 63) >> 1;    // K-step within split
    const int ksi = kb & 1;            // 32-k half
    __bf16* dstb = Bp + (size_t)(s * NST + st) * BSTEP_ELEM
                      + (size_t)ksi * BHALF_ELEM;
#pragma unroll
    for (int i = 0; i < 2; ++i) {
        int idx = i * 256 + t;         // 0..511 = 4 planes x 128 u
        int p = idx >> 7, u = idx & 127;
        bf16x8 v;
#pragma unroll
        for (int j = 0; j < 8; ++j)
            v[j] = (__bf16)tile[p * 8 + j][u];
        *(bf16x8*)&dstb[((size_t)p * 384 + mat * U_DIM + u) * 8] = v;
    }
}

// ---------------------------------------------------------------------------
// Kernel 2: fused gelu-feat + 3-way GEMM, half-step pipelined B-staging.
// grid = (KSPL=4, TOK/64=128) = 512 WGs = 2 WGs/CU (desynchronized!),
// 512 thr (8 waves = 2m x 4n), acc[2][6]. __launch_bounds__(512,4) ->
// <=128 regs -> 4 waves/SIMD resident from two independent WGs.
// LDS 79.4 KB: B half-dbuf 48K + A dbuf 18.4K + x/fw/fb 12.5K.
// Per half-step: lgkm-barrier; issue 3 gloads/wave (next half); gelu
// (h0: next step's A); ds_read + 12 MFMA; vmcnt(0) (~500cy after issue).
// XCD id%8 in {s, s+4}: one k-split per XCD, B slice L2-resident.
// ---------------------------------------------------------------------------
__global__ __launch_bounds__(512, 4) void vsn_gemm8(
    const float* __restrict__ x,
    const float* __restrict__ fw,
    const float* __restrict__ fb,
    const __bf16* __restrict__ Bp,
    __bf16* __restrict__ Hp)
{
    __shared__ __bf16 b_lds[2][BHALF_ELEM];   // 48 KB
    __shared__ __bf16 a_lds[2][BM][ASTR];     // 18.4 KB
    __shared__ float  x_lds[BM][NF + 1];      // 4.3 KB
    __shared__ __bf16 fw_lds[KRANGE];         // 4 KB
    __shared__ __bf16 fb_lds[KRANGE];         // 4 KB

    const int t    = threadIdx.x;
    const int wave = t >> 6;
    const int lane = t & 63;
    const int s     = blockIdx.x;
    const int tok0  = blockIdx.y * BM;
    const int kbase = s * KRANGE;
    const int wm = wave >> 2;                 // 0..1 : 32-row band
    const int wn = wave & 3;                  // 0..3 : 96-col band
    const int lr  = lane & 15;
    const int pl  = lane >> 4;                // k-plane 0..3
    const int lk8 = pl * 8;

    // ---- stage x (64x16), fw/fb (2048 each)
#pragma unroll
    for (int i = 0; i < 2; ++i) {
        int idx = i * 512 + t;
        x_lds[idx >> 4][idx & 15] = x[(size_t)(tok0 + (idx >> 4)) * F_DIM
                                      + (kbase >> 7) + (idx & 15)];
        {
            int k2 = idx * 2;
            __bf16 w0 = (__bf16)fw[kbase + k2],     w1 = (__bf16)fw[kbase + k2 + 1];
            __bf16 b0 = (__bf16)fb[kbase + k2],     b1 = (__bf16)fb[kbase + k2 + 1];
            fw_lds[k2] = w0; fw_lds[k2 + 1] = w1;
            fb_lds[k2] = b0; fb_lds[k2 + 1] = b1;
        }
    }

    f32x4 acc[2][6];
#pragma unroll
    for (int i = 0; i < 2; ++i)
#pragma unroll
        for (int j = 0; j < 6; ++j)
            acc[i][j] = (f32x4){0.f, 0.f, 0.f, 0.f};

    const int m_a = t >> 3;          // 0..63 : A row this thread computes
    const int kk  = (t & 7) * 8;     // 0..56 : A k-subcol (8 elems)

    auto gelu_write = [&](int st, int buf) {
        const int k0 = st * BK;
        const float xs = x_lds[m_a][(k0 + kk) >> 7];
        bf16x8 wv = *(const bf16x8*)&fw_lds[k0 + kk];
        bf16x8 bv = *(const bf16x8*)&fb_lds[k0 + kk];
        bf16x8 av;
#pragma unroll
        for (int j = 0; j < 8; ++j) {
            float z = fmaf(xs, (float)wv[j], (float)bv[j]);
            av[j] = (__bf16)gelu_fast(z);
        }
        *(bf16x8*)&a_lds[buf][m_a][kk] = av;
    };

    // B half stage: 24 chunks of 1KB; wave w copies chunks [3w, 3w+3)
    const char* bsrc = (const char*)Bp + (size_t)(s * NST) * BSTEP_BYTES
                                       + (size_t)wave * 3 * 1024;
    auto stageB = [&](int g, int buf) {   // g = global half index
        const char* src = bsrc + (size_t)g * BHALF_BYTES;
        char* dst = (char*)&b_lds[buf][0] + wave * 3 * 1024;
#pragma unroll
        for (int c = 0; c < 3; ++c)
            gload16(src + c * 1024, dst + c * 1024, lane);
    };

    stageB(0, 0);
    asm volatile("s_waitcnt vmcnt(0) lgkmcnt(0)" ::: "memory");
    __builtin_amdgcn_s_barrier();
    __builtin_amdgcn_sched_barrier(0);
    gelu_write(0, 0);                 // A for step 0 (published at loop-top)

    for (int g = 0; g < NHALF; ++g) {
        const int st   = g >> 1;
        const int h    = g & 1;
        const int bbuf = g & 1;
        const int abuf = st & 1;
        WG_SYNC();                    // b[bbuf], a[abuf] visible

        if (g + 1 < NHALF)
            stageB(g + 1, bbuf ^ 1);          // async; lands by next barrier
        if (h == 0 && st + 1 < NST)
            gelu_write(st + 1, abuf ^ 1);     // VALU hides stage latency

        bf16x8 bf[6];
#pragma unroll
        for (int j = 0; j < 6; ++j)
            bf[j] = *(const bf16x8*)
                &b_lds[bbuf][((pl * 384) + wn * 96 + j * 16 + lr) * 8];
        bf16x8 af[2];
#pragma unroll
        for (int i = 0; i < 2; ++i)
            af[i] = *(const bf16x8*)
                &a_lds[abuf][wm * 32 + i * 16 + lr][h * 32 + lk8];

        __builtin_amdgcn_s_setprio(1);
#pragma unroll
        for (int i = 0; i < 2; ++i)
#pragma unroll
            for (int j = 0; j < 6; ++j)
                acc[i][j] = __builtin_amdgcn_mfma_f32_16x16x32_bf16(
                    af[i], bf[j], acc[i][j], 0, 0, 0);
        __builtin_amdgcn_s_setprio(0);

        if (g + 1 < NHALF)
            asm volatile("s_waitcnt vmcnt(0)" ::: "memory");  // next half landed
    }

    // ---- write bf16 partials (C/D: col=lane&15, row=(lane>>4)*4+r)
    __bf16* Hs = Hp + (size_t)s * ((size_t)TOK * N3);
    const int r0 = (lane >> 4) * 4;
#pragma unroll
    for (int i = 0; i < 2; ++i)
#pragma unroll
        for (int j = 0; j < 6; ++j)
#pragma unroll
            for (int r = 0; r < 4; ++r)
                Hs[(size_t)(tok0 + wm * 32 + i * 16 + r0 + r) * N3
                   + wn * 96 + j * 16 + lr] = (__bf16)acc[i][j][r];
}

// ---------------------------------------------------------------------------
// Kernel 3: epilogue. grid = TOK/16 = 512 WGs x 256 thr; wave = 4 tokens.
// Lane l owns feature pair (2l, 2l+1); shfl-broadcast matmuls over 4 tokens.
// ---------------------------------------------------------------------------
__global__ __launch_bounds__(256) void vsn_epi8(
    const float* __restrict__ x,
    const __bf16* __restrict__ Hp,
    const unsigned* __restrict__ linp,
    const float* __restrict__ elu_b,
    const float* __restrict__ lin_b,
    const float* __restrict__ gate_b,
    const float* __restrict__ ln_g,
    const float* __restrict__ ln_b,
    const float* __restrict__ sm_w,
    const float* __restrict__ sm_b,
    float* __restrict__ out)
{
    __shared__ unsigned lin_lds[U_DIM * 64];     // 32 KB (bf16 pairs)
    __shared__ float    smw_lds[U_DIM * F_DIM];  // 32 KB
    const int t = threadIdx.x, wave = t >> 6, lane = t & 63;
    const int tokb = blockIdx.x * 16 + wave * 4;

    {
        const uint4* l4 = (const uint4*)linp;
        uint4* d4 = (uint4*)lin_lds;
#pragma unroll
        for (int i = 0; i < 8; ++i) d4[i * 256 + t] = l4[i * 256 + t];
        const f32x4* s4 = (const f32x4*)sm_w;
        f32x4* m4 = (f32x4*)smw_lds;
#pragma unroll
        for (int i = 0; i < 8; ++i) m4[i * 256 + t] = s4[i * 256 + t];
    }
    __syncthreads();

    const float2 eb  = *(const float2*)&elu_b[2 * lane];
    const float2 gb  = *(const float2*)&gate_b[2 * lane];
    const float2 lb  = *(const float2*)&lin_b[2 * lane];
    const float2 lg2 = *(const float2*)&ln_g[2 * lane];
    const float2 lnb = *(const float2*)&ln_b[2 * lane];
    const float  smb = sm_b[lane];

    float h1a[4], h1b[4], ga[4], gbt[4], pa[4], pb[4];
#pragma unroll
    for (int tk = 0; tk < 4; ++tk) {
        const unsigned short* base =
            (const unsigned short*)Hp + (size_t)(tokb + tk) * N3;
        float a0 = 0.f, a1 = 0.f, g0 = 0.f, g1 = 0.f, p0 = 0.f, p1 = 0.f;
#pragma unroll
        for (int s = 0; s < KSPL; ++s) {
            const unsigned short* bs = base + (size_t)s * TOK * N3;
            unsigned ua = *(const unsigned*)(bs + 2 * lane);
            unsigned ug = *(const unsigned*)(bs + 128 + 2 * lane);
            unsigned up = *(const unsigned*)(bs + 256 + 2 * lane);
            a0 += bflo(ua); a1 += bfhi(ua);
            g0 += bflo(ug); g1 += bfhi(ug);
            p0 += bflo(up); p1 += bfhi(up);
        }
        float e0 = a0 + eb.x, e1 = a1 + eb.y;
        h1a[tk] = (e0 > 0.f) ? e0 : expm1f(e0);
        h1b[tk] = (e1 > 0.f) ? e1 : expm1f(e1);
        ga[tk]  = 1.f / (1.f + __expf(-(g0 + gb.x)));
        gbt[tk] = 1.f / (1.f + __expf(-(g1 + gb.y)));
        pa[tk] = p0; pb[tk] = p1;
    }

    // h2 = h1 @ lin_w + lin_b  (shfl-broadcast, 4 tokens jointly)
    float h2a[4] = {lb.x, lb.x, lb.x, lb.x};
    float h2b[4] = {lb.y, lb.y, lb.y, lb.y};
#pragma unroll 2
    for (int v = 0; v < U_DIM; v += 2) {
        unsigned lwA = lin_lds[v * 64 + lane];
        unsigned lwB = lin_lds[(v + 1) * 64 + lane];
        float wAx = bflo(lwA), wAy = bfhi(lwA);
        float wBx = bflo(lwB), wBy = bfhi(lwB);
        const int src = v >> 1;
#pragma unroll
        for (int tk = 0; tk < 4; ++tk) {
            float hvA = __shfl(h1a[tk], src);
            float hvB = __shfl(h1b[tk], src);
            h2a[tk] = fmaf(hvA, wAx, fmaf(hvB, wBx, h2a[tk]));
            h2b[tk] = fmaf(hvA, wAy, fmaf(hvB, wBy, h2b[tk]));
        }
    }

    // gate/residual + LayerNorm -> y pairs
    float ya[4], yb[4];
#pragma unroll
    for (int tk = 0; tk < 4; ++tk) {
        float h0 = ga[tk] * h2a[tk] + pa[tk];
        float h1 = gbt[tk] * h2b[tk] + pb[tk];
        float sum = h0 + h1;
#pragma unroll
        for (int off = 32; off; off >>= 1) sum += __shfl_xor(sum, off);
        float mu = sum * (1.0f / 128.0f);
        float d0 = h0 - mu, d1 = h1 - mu;
        float vq = d0 * d0 + d1 * d1;
#pragma unroll
        for (int off = 32; off; off >>= 1) vq += __shfl_xor(vq, off);
        float rstd = rsqrtf(vq * (1.0f / 128.0f) + 1e-3f);
        ya[tk] = d0 * rstd * lg2.x + lnb.x;
        yb[tk] = d1 * rstd * lg2.y + lnb.y;
    }

    // logits = y @ sm_w + sm_b  (lane = feature f)
    float lgt[4] = {smb, smb, smb, smb};
#pragma unroll 2
    for (int u = 0; u < U_DIM; u += 2) {
        float swA = smw_lds[u * F_DIM + lane];
        float swB = smw_lds[(u + 1) * F_DIM + lane];
        const int src = u >> 1;
#pragma unroll
        for (int tk = 0; tk < 4; ++tk) {
            float yvA = __shfl(ya[tk], src);
            float yvB = __shfl(yb[tk], src);
            lgt[tk] = fmaf(yvA, swA, fmaf(yvB, swB, lgt[tk]));
        }
    }

    // softmax over 64 lanes + outputs
#pragma unroll
    for (int tk = 0; tk < 4; ++tk) {
        const int tok = tokb + tk;
        float mx = lgt[tk];
#pragma unroll
        for (int off = 32; off; off >>= 1) mx = fmaxf(mx, __shfl_xor(mx, off));
        float ex = __expf(lgt[tk] - mx);
        float se = ex;
#pragma unroll
        for (int off = 32; off; off >>= 1) se += __shfl_xor(se, off);
        float wgt = ex / se;
        float xv = x[(size_t)tok * F_DIM + lane];
        out[(size_t)tok * F_DIM + lane] = xv * wgt;
        out[(size_t)TOK * F_DIM + (size_t)tok * F_DIM + lane] = wgt;
    }
}

// ---------------------------------------------------------------------------
extern "C" void kernel_launch(void* const* d_in, const int* in_sizes, int n_in,
                              void* d_out, int out_size, void* d_ws, size_t ws_size,
                              hipStream_t stream)
{
    const float* x      = (const float*)d_in[0];
    const float* fw     = (const float*)d_in[1];
    const float* fb     = (const float*)d_in[2];
    const float* elu_w  = (const float*)d_in[3];
    const float* elu_b  = (const float*)d_in[4];
    const float* lin_w  = (const float*)d_in[5];
    const float* lin_b  = (const float*)d_in[6];
    const float* gate_w = (const float*)d_in[7];
    const float* gate_b = (const float*)d_in[8];
    const float* proj_w = (const float*)d_in[9];
    const float* ln_g   = (const float*)d_in[10];
    const float* ln_b   = (const float*)d_in[11];
    const float* sm_w   = (const float*)d_in[12];
    const float* sm_b   = (const float*)d_in[13];

    // ws: Bp 6.29 MB | Hp (4 x bf16 partials) 25.17 MB | linp 32 KB
    char* wsb = (char*)d_ws;
    __bf16*   Bp   = (__bf16*)wsb;
    __bf16*   Hp   = (__bf16*)(wsb + (size_t)N3 * KDIM * sizeof(__bf16));
    unsigned* linp = (unsigned*)(wsb + (size_t)N3 * KDIM * sizeof(__bf16)
                                     + (size_t)KSPL * TOK * N3 * sizeof(__bf16));

    vsn_prep8<<<3 * (KDIM / 32) + 1, 256, 0, stream>>>(elu_w, gate_w, proj_w,
                                                       lin_w, Bp, linp);
    vsn_gemm8<<<dim3(KSPL, TOK / BM), 512, 0, stream>>>(x, fw, fb, Bp, Hp);
    vsn_epi8<<<TOK / 16, 256, 0, stream>>>(x, Hp, linp, elu_b, lin_b, gate_b,
                                           ln_g, ln_b, sm_w, sm_b, (float*)d_out);
}

// Round 9
// 88.038 us; speedup vs baseline: 1.2742x; 1.2742x over previous
//
#include <hip/hip_runtime.h>
#include <hip/hip_bf16.h>
#include <math.h>

// Problem dims
#define TOK   8192
#define KDIM  8192
#define F_DIM 64
#define U_DIM 128
#define N3    384

// GEMM tiling (R4 structure, proven 73 us)
#define BM    64
#define BK    64
#define KSPL  4
#define KRANGE (KDIM / KSPL)     // 2048
#define NST   (KRANGE / BK)      // 32
#define NF    (KRANGE / U_DIM)   // 16
#define ASTR  72

typedef __bf16 bf16x8 __attribute__((ext_vector_type(8)));
typedef float  f32x4  __attribute__((ext_vector_type(4)));

// lgkmcnt-only barrier: LDS drained; global loads stay in flight
#define WG_SYNC() do {                                       \
    asm volatile("s_waitcnt lgkmcnt(0)" ::: "memory");       \
    __builtin_amdgcn_s_barrier();                            \
    __builtin_amdgcn_sched_barrier(0);                       \
} while (0)

// tanh-approx GELU: z - z/(1 + 2^(z*(2.30234 + 0.102955 z^2))), |err| < ~1e-3
__device__ __forceinline__ float gelu_fast(float z) {
    float t = z * z;
    float s = fmaf(0.1029551f, t, 2.3023457f);
    float e = __builtin_amdgcn_exp2f(z * s);
    float r = __builtin_amdgcn_rcpf(e + 1.0f);   // +inf -> 0
    return fmaf(-z, r, z);
}

__device__ __forceinline__ float bflo(unsigned u) { u <<= 16; return __builtin_bit_cast(float, u); }
__device__ __forceinline__ float bfhi(unsigned u) { u &= 0xffff0000u; return __builtin_bit_cast(float, u); }
__device__ __forceinline__ unsigned bfpack(float a, float b) {
    unsigned pa = (unsigned)__builtin_bit_cast(unsigned short, (__bf16)a);
    unsigned pb = (unsigned)__builtin_bit_cast(unsigned short, (__bf16)b);
    return pa | (pb << 16);
}

// ---------------------------------------------------------------------------
// Kernel 1: blocks 0..767: pack W[k][n] f32 (3 mats) -> Bp[k/32][n(384)][k%32]
// bf16 (R4 layout). Blocks 768..775: lin_w -> MFMA B-frag order
// linf[(ks*8+nj)*512 + lane*8 + j] (k=ks*32+(lane>>4)*8+j, n=nj*16+(lane&15)).
// Blocks 776..779: sm_w -> smf[(ks*4+nj)*512 + lane*8 + j] (n over F=64).
// ---------------------------------------------------------------------------
__global__ __launch_bounds__(256) void vsn_prep9(
    const float* __restrict__ elu_w,
    const float* __restrict__ gate_w,
    const float* __restrict__ proj_w,
    const float* __restrict__ lin_w,
    const float* __restrict__ sm_w,
    __bf16* __restrict__ Bp,
    __bf16* __restrict__ linf,
    __bf16* __restrict__ smf)
{
    const int t = threadIdx.x;
    const int bx = blockIdx.x;
    if (bx >= 3 * (KDIM / 32)) {
        int xb = bx - 3 * (KDIM / 32);
        if (xb < 8) {
            // linf: 16384 elems, 2048 per block
#pragma unroll
            for (int i = 0; i < 8; ++i) {
                int idx = xb * 2048 + i * 256 + t;
                int j = idx & 7, l = (idx >> 3) & 63, q = idx >> 9;
                int ks = q >> 3, nj = q & 7;
                int k = ks * 32 + (l >> 4) * 8 + j;
                int n = nj * 16 + (l & 15);
                linf[idx] = (__bf16)lin_w[k * U_DIM + n];
            }
        } else {
            // smf: 8192 elems, 2048 per block
            int sb = xb - 8;
#pragma unroll
            for (int i = 0; i < 8; ++i) {
                int idx = sb * 2048 + i * 256 + t;
                int j = idx & 7, l = (idx >> 3) & 63, q = idx >> 9;
                int ks = q >> 2, nj = q & 3;
                int k = ks * 32 + (l >> 4) * 8 + j;
                int n = nj * 16 + (l & 15);
                smf[idx] = (__bf16)sm_w[k * F_DIM + n];
            }
        }
        return;
    }
    __shared__ float tile[32][U_DIM + 1];
    const int mat = bx / (KDIM / 32);
    const int kb  = bx % (KDIM / 32);
    const float* W = (mat == 0) ? elu_w : (mat == 1 ? gate_w : proj_w);

#pragma unroll
    for (int i = 0; i < 16; ++i) {
        int idx = i * 256 + t;
        int r = idx >> 7, c = idx & 127;
        tile[r][c] = W[(size_t)(kb * 32 + r) * U_DIM + c];
    }
    __syncthreads();
#pragma unroll
    for (int i = 0; i < 16; ++i) {
        int idx = i * 256 + t;
        int c = idx >> 5, r = idx & 31;
        Bp[((size_t)kb * N3 + mat * U_DIM + c) * 32 + r] = (__bf16)tile[r][c];
    }
}

// ---------------------------------------------------------------------------
// Kernel 2: fused gelu-feat + 3-way GEMM (R4 structure, verbatim).
// grid = (KSPL=4, TOK/BM=128), 256 thr (4 waves, wave = 96 n-cols, acc[4][6]).
// XCD id%8 in {s, s+4}: one k-split per XCD (B L2-resident).
// ---------------------------------------------------------------------------
__global__ __launch_bounds__(256, 2) void vsn_gemm9(
    const float* __restrict__ x,
    const float* __restrict__ fw,
    const float* __restrict__ fb,
    const __bf16* __restrict__ Bp,
    __bf16* __restrict__ Hp)
{
    __shared__ float  x_lds[BM][NF + 1];
    __shared__ __bf16 fw_lds[KRANGE];
    __shared__ __bf16 fb_lds[KRANGE];
    __shared__ __bf16 a_lds[2][BM][ASTR];

    const int t    = threadIdx.x;
    const int wave = t >> 6;
    const int lane = t & 63;
    const int s     = blockIdx.x;
    const int tok0  = blockIdx.y * BM;
    const int kbase = s * KRANGE;
    const int nbase = wave * 96;
    const int lr  = lane & 15;
    const int lk8 = (lane >> 4) * 8;

#pragma unroll
    for (int i = 0; i < (BM * NF) / 256; ++i) {
        int idx = i * 256 + t;
        int r = idx >> 4, c = idx & 15;
        x_lds[r][c] = x[(size_t)(tok0 + r) * F_DIM + (kbase >> 7) + c];
    }
#pragma unroll
    for (int i = 0; i < KRANGE / 256; ++i) {
        int k = i * 256 + t;
        fw_lds[k] = (__bf16)fw[kbase + k];
        fb_lds[k] = (__bf16)fb[kbase + k];
    }

    f32x4 acc[4][6];
#pragma unroll
    for (int i = 0; i < 4; ++i)
#pragma unroll
        for (int j = 0; j < 6; ++j)
            acc[i][j] = (f32x4){0.f, 0.f, 0.f, 0.f};

    const int m_a = t >> 2;
    const int kk  = (t & 3) * 16;

    auto gelu_write = [&](int st, int buf) {
        const int k0 = st * BK;
        const float xs = x_lds[m_a][(k0 + kk) >> 7];
#pragma unroll
        for (int h = 0; h < 2; ++h) {
            bf16x8 wv = *(const bf16x8*)&fw_lds[k0 + kk + h * 8];
            bf16x8 bv = *(const bf16x8*)&fb_lds[k0 + kk + h * 8];
            bf16x8 av;
#pragma unroll
            for (int j = 0; j < 8; ++j) {
                float z = fmaf(xs, (float)wv[j], (float)bv[j]);
                av[j] = (__bf16)gelu_fast(z);
            }
            *(bf16x8*)&a_lds[buf][m_a][kk + h * 8] = av;
        }
    };

    const __bf16* bb = Bp + (size_t)(kbase >> 5) * (N3 * 32)
                          + (nbase + lr) * 32 + lk8;
    auto loadB = [&](int st, int ksi, bf16x8 (&dst)[6]) {
        const __bf16* p = bb + (size_t)(st * 2 + ksi) * (N3 * 32);
#pragma unroll
        for (int j = 0; j < 6; ++j)
            dst[j] = *(const bf16x8*)(p + j * 512);
    };

    bf16x8 bX[6], bY[6];

    WG_SYNC();
    gelu_write(0, 0);
    loadB(0, 0, bX);

    for (int st = 0; st < NST - 1; ++st) {
        const int cur = st & 1;
        WG_SYNC();
        loadB(st, 1, bY);
        gelu_write(st + 1, cur ^ 1);

        bf16x8 af[4];
#pragma unroll
        for (int i = 0; i < 4; ++i)
            af[i] = *(const bf16x8*)&a_lds[cur][i * 16 + lr][lk8];
#pragma unroll
        for (int i = 0; i < 4; ++i)
#pragma unroll
            for (int j = 0; j < 6; ++j)
                acc[i][j] = __builtin_amdgcn_mfma_f32_16x16x32_bf16(
                    af[i], bX[j], acc[i][j], 0, 0, 0);

        loadB(st + 1, 0, bX);
#pragma unroll
        for (int i = 0; i < 4; ++i)
            af[i] = *(const bf16x8*)&a_lds[cur][i * 16 + lr][32 + lk8];
#pragma unroll
        for (int i = 0; i < 4; ++i)
#pragma unroll
            for (int j = 0; j < 6; ++j)
                acc[i][j] = __builtin_amdgcn_mfma_f32_16x16x32_bf16(
                    af[i], bY[j], acc[i][j], 0, 0, 0);
    }
    {
        const int cur = (NST - 1) & 1;
        WG_SYNC();
        loadB(NST - 1, 1, bY);
        bf16x8 af[4];
#pragma unroll
        for (int i = 0; i < 4; ++i)
            af[i] = *(const bf16x8*)&a_lds[cur][i * 16 + lr][lk8];
#pragma unroll
        for (int i = 0; i < 4; ++i)
#pragma unroll
            for (int j = 0; j < 6; ++j)
                acc[i][j] = __builtin_amdgcn_mfma_f32_16x16x32_bf16(
                    af[i], bX[j], acc[i][j], 0, 0, 0);
#pragma unroll
        for (int i = 0; i < 4; ++i)
            af[i] = *(const bf16x8*)&a_lds[cur][i * 16 + lr][32 + lk8];
#pragma unroll
        for (int i = 0; i < 4; ++i)
#pragma unroll
            for (int j = 0; j < 6; ++j)
                acc[i][j] = __builtin_amdgcn_mfma_f32_16x16x32_bf16(
                    af[i], bY[j], acc[i][j], 0, 0, 0);
    }

    __bf16* Hs = Hp + (size_t)s * ((size_t)TOK * N3);
    const int r0 = (lane >> 4) * 4;
#pragma unroll
    for (int i = 0; i < 4; ++i)
#pragma unroll
        for (int j = 0; j < 6; ++j)
#pragma unroll
            for (int r = 0; r < 4; ++r)
                Hs[(size_t)(tok0 + i * 16 + r0 + r) * N3 + nbase + j * 16 + lr]
                    = (__bf16)acc[i][j][r];
}

// ---------------------------------------------------------------------------
// Kernel 3: MFMA epilogue. grid = 256 WGs x 128 thr (2 waves); 16 tok/wave.
// Pointwise (coalesced) -> h1/gate/proj LDS -> 32 MFMA (h2 = h1@lin_w) ->
// gate*h2+proj -> LN (16-lane-group shfl reduce; C-layout row=(l>>4)*4+r,
// col=(l&15)+16nj) -> y LDS -> 16 MFMA (logits) -> softmax -> stores.
// Replaces ~1280 ds_bpermute/wave with ~48 MFMA + ~130 LDS ops.
// ---------------------------------------------------------------------------
__global__ __launch_bounds__(128) void vsn_epi9(
    const float* __restrict__ x,
    const __bf16* __restrict__ Hp,
    const __bf16* __restrict__ linf,
    const __bf16* __restrict__ smf,
    const float* __restrict__ elu_b,
    const float* __restrict__ lin_b,
    const float* __restrict__ gate_b,
    const float* __restrict__ ln_g,
    const float* __restrict__ ln_b,
    const float* __restrict__ sm_b,
    float* __restrict__ out)
{
    __shared__ __bf16 linf_lds[32 * 512];      // 32 KB: (ks*8+nj)*512 + l*8 + j
    __shared__ __bf16 smf_lds[16 * 512];       // 16 KB
    __shared__ __bf16 h1_lds[2][16][136];      // bf16, reused for y
    __shared__ float  g_lds[2][16][132];
    __shared__ float  p_lds[2][16][132];

    const int t = threadIdx.x, w = t >> 6, lane = t & 63;
    const int tokb = blockIdx.x * 32 + w * 16;

    // ---- stage weight fragments (both waves cooperate)
    {
        const uint4* s4 = (const uint4*)linf;
        uint4* d4 = (uint4*)linf_lds;
#pragma unroll
        for (int i = 0; i < 16; ++i) d4[i * 128 + t] = s4[i * 128 + t];
        const uint4* s2 = (const uint4*)smf;
        uint4* d2 = (uint4*)smf_lds;
#pragma unroll
        for (int i = 0; i < 8; ++i) d2[i * 128 + t] = s2[i * 128 + t];
    }

    // ---- phase A: pointwise over 16 tokens; lane covers cols 2l, 2l+1
    const float2 eb = *(const float2*)&elu_b[2 * lane];
    const float2 gb = *(const float2*)&gate_b[2 * lane];
#pragma unroll 4
    for (int tk = 0; tk < 16; ++tk) {
        const unsigned short* base =
            (const unsigned short*)Hp + (size_t)(tokb + tk) * N3;
        float a0 = 0.f, a1 = 0.f, g0 = 0.f, g1 = 0.f, p0 = 0.f, p1 = 0.f;
#pragma unroll
        for (int s = 0; s < KSPL; ++s) {
            const unsigned short* bs = base + (size_t)s * TOK * N3;
            unsigned ua = *(const unsigned*)(bs + 2 * lane);
            unsigned ug = *(const unsigned*)(bs + 128 + 2 * lane);
            unsigned up = *(const unsigned*)(bs + 256 + 2 * lane);
            a0 += bflo(ua); a1 += bfhi(ua);
            g0 += bflo(ug); g1 += bfhi(ug);
            p0 += bflo(up); p1 += bfhi(up);
        }
        float e0 = a0 + eb.x, e1 = a1 + eb.y;
        float h10 = (e0 > 0.f) ? e0 : expm1f(e0);
        float h11 = (e1 > 0.f) ? e1 : expm1f(e1);
        *(unsigned*)((char*)&h1_lds[w][tk][0] + 4 * lane) = bfpack(h10, h11);
        g_lds[w][tk][2 * lane]     = 1.f / (1.f + __expf(-(g0 + gb.x)));
        g_lds[w][tk][2 * lane + 1] = 1.f / (1.f + __expf(-(g1 + gb.y)));
        p_lds[w][tk][2 * lane]     = p0;
        p_lds[w][tk][2 * lane + 1] = p1;
    }
    __syncthreads();   // weights staged + all per-wave LDS written

    const int c0 = lane & 15;
    const int rg = lane >> 4;   // rows rg*4 + r

    // ---- h2 = h1 @ lin_w (32 MFMA)
    f32x4 acc[8];
#pragma unroll
    for (int nj = 0; nj < 8; ++nj) acc[nj] = (f32x4){0.f, 0.f, 0.f, 0.f};
#pragma unroll
    for (int ks = 0; ks < 4; ++ks) {
        bf16x8 af = *(const bf16x8*)&h1_lds[w][c0][ks * 32 + rg * 8];
#pragma unroll
        for (int nj = 0; nj < 8; ++nj) {
            bf16x8 bf = *(const bf16x8*)&linf_lds[((ks * 8 + nj) * 64 + lane) * 8];
            acc[nj] = __builtin_amdgcn_mfma_f32_16x16x32_bf16(af, bf, acc[nj], 0, 0, 0);
        }
    }

    // ---- h = gate * (h2 + lin_b) + proj
    float h[8][4];
#pragma unroll
    for (int nj = 0; nj < 8; ++nj) {
        float lb = lin_b[c0 + 16 * nj];
#pragma unroll
        for (int r = 0; r < 4; ++r) {
            int tokr = rg * 4 + r;
            float h2 = acc[nj][r] + lb;
            float g  = g_lds[w][tokr][c0 + 16 * nj];
            float p  = p_lds[w][tokr][c0 + 16 * nj];
            h[nj][r] = fmaf(g, h2, p);
        }
    }

    // ---- LayerNorm per row (16-lane-group shfl reduce)
    float mu[4], rstd[4];
#pragma unroll
    for (int r = 0; r < 4; ++r) {
        float s = 0.f;
#pragma unroll
        for (int nj = 0; nj < 8; ++nj) s += h[nj][r];
        s += __shfl_xor(s, 1); s += __shfl_xor(s, 2);
        s += __shfl_xor(s, 4); s += __shfl_xor(s, 8);
        mu[r] = s * (1.0f / 128.0f);
        float v = 0.f;
#pragma unroll
        for (int nj = 0; nj < 8; ++nj) {
            float d = h[nj][r] - mu[r];
            v = fmaf(d, d, v);
        }
        v += __shfl_xor(v, 1); v += __shfl_xor(v, 2);
        v += __shfl_xor(v, 4); v += __shfl_xor(v, 8);
        rstd[r] = rsqrtf(v * (1.0f / 128.0f) + 1e-3f);
    }

    // ---- y -> LDS (reuse h1_lds; same-wave DS ordering is in-order)
#pragma unroll
    for (int nj = 0; nj < 8; ++nj) {
        int col = c0 + 16 * nj;
        float lg = ln_g[col], lb = ln_b[col];
#pragma unroll
        for (int r = 0; r < 4; ++r) {
            float y = fmaf((h[nj][r] - mu[r]) * rstd[r], lg, lb);
            h1_lds[w][rg * 4 + r][col] = (__bf16)y;
        }
    }

    // ---- logits = y @ sm_w (16 MFMA)
    f32x4 acc2[4];
#pragma unroll
    for (int nj = 0; nj < 4; ++nj) acc2[nj] = (f32x4){0.f, 0.f, 0.f, 0.f};
#pragma unroll
    for (int ks = 0; ks < 4; ++ks) {
        bf16x8 af = *(const bf16x8*)&h1_lds[w][c0][ks * 32 + rg * 8];
#pragma unroll
        for (int nj = 0; nj < 4; ++nj) {
            bf16x8 bf = *(const bf16x8*)&smf_lds[((ks * 4 + nj) * 64 + lane) * 8];
            acc2[nj] = __builtin_amdgcn_mfma_f32_16x16x32_bf16(af, bf, acc2[nj], 0, 0, 0);
        }
    }

    // ---- softmax over 64 features per row + outputs
    float lgt[4][4];
#pragma unroll
    for (int nj = 0; nj < 4; ++nj) {
        float sb = sm_b[c0 + 16 * nj];
#pragma unroll
        for (int r = 0; r < 4; ++r) lgt[nj][r] = acc2[nj][r] + sb;
    }
#pragma unroll
    for (int r = 0; r < 4; ++r) {
        float mx = fmaxf(fmaxf(lgt[0][r], lgt[1][r]), fmaxf(lgt[2][r], lgt[3][r]));
        mx = fmaxf(mx, __shfl_xor(mx, 1)); mx = fmaxf(mx, __shfl_xor(mx, 2));
        mx = fmaxf(mx, __shfl_xor(mx, 4)); mx = fmaxf(mx, __shfl_xor(mx, 8));
        float ex[4], se = 0.f;
#pragma unroll
        for (int nj = 0; nj < 4; ++nj) {
            ex[nj] = __expf(lgt[nj][r] - mx);
            se += ex[nj];
        }
        se += __shfl_xor(se, 1); se += __shfl_xor(se, 2);
        se += __shfl_xor(se, 4); se += __shfl_xor(se, 8);
        float inv = 1.0f / se;
        int tok = tokb + rg * 4 + r;
#pragma unroll
        for (int nj = 0; nj < 4; ++nj) {
            int f = c0 + 16 * nj;
            float wgt = ex[nj] * inv;
            float xv = x[(size_t)tok * F_DIM + f];
            out[(size_t)tok * F_DIM + f] = xv * wgt;
            out[(size_t)TOK * F_DIM + (size_t)tok * F_DIM + f] = wgt;
        }
    }
}

// ---------------------------------------------------------------------------
extern "C" void kernel_launch(void* const* d_in, const int* in_sizes, int n_in,
                              void* d_out, int out_size, void* d_ws, size_t ws_size,
                              hipStream_t stream)
{
    const float* x      = (const float*)d_in[0];
    const float* fw     = (const float*)d_in[1];
    const float* fb     = (const float*)d_in[2];
    const float* elu_w  = (const float*)d_in[3];
    const float* elu_b  = (const float*)d_in[4];
    const float* lin_w  = (const float*)d_in[5];
    const float* lin_b  = (const float*)d_in[6];
    const float* gate_w = (const float*)d_in[7];
    const float* gate_b = (const float*)d_in[8];
    const float* proj_w = (const float*)d_in[9];
    const float* ln_g   = (const float*)d_in[10];
    const float* ln_b   = (const float*)d_in[11];
    const float* sm_w   = (const float*)d_in[12];
    const float* sm_b   = (const float*)d_in[13];

    // ws: Bp 6.29 MB | Hp (4 x bf16 partials) 25.17 MB | linf 32 KB | smf 16 KB
    char* wsb = (char*)d_ws;
    __bf16* Bp   = (__bf16*)wsb;
    __bf16* Hp   = (__bf16*)(wsb + (size_t)N3 * KDIM * sizeof(__bf16));
    __bf16* linf = (__bf16*)(wsb + (size_t)N3 * KDIM * sizeof(__bf16)
                                 + (size_t)KSPL * TOK * N3 * sizeof(__bf16));
    __bf16* smf  = linf + U_DIM * U_DIM;

    vsn_prep9<<<3 * (KDIM / 32) + 12, 256, 0, stream>>>(elu_w, gate_w, proj_w,
                                                        lin_w, sm_w, Bp, linf, smf);
    vsn_gemm9<<<dim3(KSPL, TOK / BM), 256, 0, stream>>>(x, fw, fb, Bp, Hp);
    vsn_epi9<<<TOK / 32, 128, 0, stream>>>(x, Hp, linf, smf, elu_b, lin_b,
                                           gate_b, ln_g, ln_b, sm_b, (float*)d_out);
}